// Round 1
// baseline (193.963 us; speedup 1.0000x reference)
//
#include <hip/hip_runtime.h>

// FAVOR+ causal linear attention, chunk-parallel formulation.
// B=1,H=8 -> BH=8; D=DV=64; N=2048; M=128. Chunk C=64, NC=32 chunks.
// Phase1: per-chunk S_c = phiK^T V (MxDV), z_c = sum phiK (M)  [256 blocks]
// Phase2: exclusive prefix scan of S,z over chunks               [260 blocks]
// Phase3: out = phiQ*S_prefix + causal(phiQ phiK^T) V, normed    [256 blocks]

#define BH 8
#define D 64
#define DV 64
#define NSEQ 2048
#define M 128
#define CHK 64
#define NC (NSEQ / CHK)              // 32
#define PHI_SCALE 0.08838834764831845f  // 1/sqrt(128)

__global__ __launch_bounds__(256) void favor_phase1(
    const float* __restrict__ keys, const float* __restrict__ values,
    const float* __restrict__ features, float* __restrict__ wsS,
    float* __restrict__ wsZ)
{
    const int bh = blockIdx.x / NC;
    const int c  = blockIdx.x % NC;
    const int n0 = c * CHK;
    const int tid = threadIdx.x;

    __shared__ float sV[DV * (CHK + 1)];  // [v][n] padded: lanes-vary-v reads are (v+n)%32 -> 2-way (free)
    __shared__ float sPhiK[M * CHK];      // [m][n]: writes stride-1, reads broadcast

    // Load V chunk (coalesced along n)
    for (int e = tid; e < DV * CHK; e += 256) {
        const int v = e >> 6, n = e & 63;
        sV[v * (CHK + 1) + n] = values[(bh * DV + v) * NSEQ + n0 + n];
    }

    // phiK[m][n] = relu(F[m,:]. K[:,n]) * scale. Lanes vary n (coalesced K), F row wave-uniform (scalar).
    const float* Kb = keys + bh * D * NSEQ + n0;
    for (int e = tid; e < M * CHK; e += 256) {
        const int m = e >> 6, n = e & 63;
        const float* Fr = features + m * D;
        float acc = 0.f;
        #pragma unroll
        for (int d = 0; d < D; ++d) acc = fmaf(Fr[d], Kb[d * NSEQ + n], acc);
        sPhiK[e] = fmaxf(acc, 0.f) * PHI_SCALE;
    }
    __syncthreads();

    // S[m][v] = sum_n phiK[m][n] * V[v][n];  z[m] = sum_n phiK[m][n]
    float* Sout = wsS + (size_t)(bh * NC + c) * M * DV;
    for (int e = tid; e < M * DV; e += 256) {
        const int m = e >> 6, v = e & 63;
        const float* pk = sPhiK + m * CHK;     // broadcast across lanes
        const float* pv = sV + v * (CHK + 1);  // 2-way banked
        float acc = 0.f;
        #pragma unroll
        for (int n = 0; n < CHK; ++n) acc = fmaf(pk[n], pv[n], acc);
        Sout[e] = acc;  // coalesced
    }
    if (tid < M) {
        const float* pk = sPhiK + tid * CHK;
        float acc = 0.f;
        #pragma unroll
        for (int n = 0; n < CHK; ++n) acc += pk[n];
        wsZ[(bh * NC + c) * M + tid] = acc;
    }
}

__global__ __launch_bounds__(256) void favor_phase2(float* __restrict__ wsS,
                                                    float* __restrict__ wsZ)
{
    const int t = blockIdx.x * 256 + threadIdx.x;
    const int PER = M * DV + M;  // 8320 entries per head
    const int bh = t / PER;
    const int i  = t - bh * PER;
    if (bh >= BH) return;
    if (i < M * DV) {
        float run = 0.f;
        float* p = wsS + (size_t)bh * NC * M * DV + i;
        for (int c = 0; c < NC; ++c) {
            const float tv = *p; *p = run; run += tv; p += M * DV;
        }
    } else {
        const int m = i - M * DV;
        float run = 0.f;
        float* p = wsZ + bh * NC * M + m;
        for (int c = 0; c < NC; ++c) {
            const float tv = *p; *p = run; run += tv; p += M;
        }
    }
}

__global__ __launch_bounds__(256) void favor_phase3(
    const float* __restrict__ keys, const float* __restrict__ values,
    const float* __restrict__ queries, const float* __restrict__ features,
    const float* __restrict__ wsS, const float* __restrict__ wsZ,
    float* __restrict__ out)
{
    const int bh = blockIdx.x / NC;
    const int c  = blockIdx.x % NC;
    const int n0 = c * CHK;
    const int tid = threadIdx.x;

    // Exactly 64 KB, staged reuse:
    //  Stage A/B/C:  [0..8192) phiQ [m][n],  [8192..16384) S then phiK^T [m][j]
    //  Stage D/E/F:  [0..4160) V [v][j] pad, [4160..8256) A [n][j],
    //                [8256..8320) norm,      [8320..12480) out staging [n][v] pad
    __shared__ float smem[16384];
    float* sPhiQ = smem;         // [m][n]: all reads broadcast or stride-1 -> conflict-free
    float* sHigh = smem + 8192;

    // Stage A: phiQ (lanes vary n -> coalesced Q, scalar F) + load exclusive-prefix S
    const float* Qb = queries + bh * D * NSEQ + n0;
    for (int e = tid; e < M * CHK; e += 256) {
        const int m = e >> 6, n = e & 63;
        const float* Fr = features + m * D;
        float acc = 0.f;
        #pragma unroll
        for (int d = 0; d < D; ++d) acc = fmaf(Fr[d], Qb[d * NSEQ + n], acc);
        sPhiQ[e] = fmaxf(acc, 0.f) * PHI_SCALE;  // e = m*64+n
    }
    const float* Sin = wsS + (size_t)(bh * NC + c) * M * DV;
    for (int e = tid; e < M * DV; e += 256) sHigh[e] = Sin[e];  // [m][v]
    __syncthreads();

    // Stage A2: inter-chunk part. Thread owns 16 (n,v) entries; n wave-uniform.
    float accO[16];
    #pragma unroll
    for (int i = 0; i < 16; ++i) {
        const int e = tid + i * 256;
        const int n = e >> 6, v = e & 63;
        float acc = 0.f;
        #pragma unroll 8
        for (int m = 0; m < M; ++m)
            acc = fmaf(sPhiQ[m * CHK + n], sHigh[m * DV + v], acc);  // bcast, stride-1
        accO[i] = acc;
    }
    float normReg = 0.f;
    if (tid < CHK) {
        const float* zp = wsZ + (bh * NC + c) * M;
        #pragma unroll 8
        for (int m = 0; m < M; ++m)
            normReg = fmaf(sPhiQ[m * CHK + tid], zp[m], normReg);  // stride-1
    }
    __syncthreads();

    // Stage B: phiK^T [m][j] into sHigh (S no longer needed)
    const float* Kb = keys + bh * D * NSEQ + n0;
    for (int e = tid; e < M * CHK; e += 256) {
        const int m = e >> 6, j = e & 63;
        const float* Fr = features + m * D;
        float acc = 0.f;
        #pragma unroll
        for (int d = 0; d < D; ++d) acc = fmaf(Fr[d], Kb[d * NSEQ + j], acc);
        sHigh[e] = fmaxf(acc, 0.f) * PHI_SCALE;
    }
    __syncthreads();

    // Stage C: A[n][j] = phiQ[n].phiK[j] (causal-masked) into registers
    float aReg[16];
    #pragma unroll
    for (int i = 0; i < 16; ++i) {
        const int e = tid + i * 256;
        const int n = e >> 6, j = e & 63;
        float acc = 0.f;
        if (j <= n) {
            #pragma unroll 8
            for (int m = 0; m < M; ++m)
                acc = fmaf(sPhiQ[m * CHK + n], sHigh[m * CHK + j], acc);
        }
        aReg[i] = acc;
    }
    __syncthreads();

    // Stage D: reuse LDS — V tile, materialize A, norm slot, out staging
    float* sV    = smem;           // [v][CHK+1] = 4160
    float* sA    = smem + 4160;    // [n][CHK]   = 4096
    float* sNorm = smem + 8256;    // 64
    float* sOut  = smem + 8320;    // [n][DV+1]  = 4160
    for (int e = tid; e < DV * CHK; e += 256) {
        const int v = e >> 6, j = e & 63;
        sV[v * (CHK + 1) + j] = values[(bh * DV + v) * NSEQ + n0 + j];
    }
    #pragma unroll
    for (int i = 0; i < 16; ++i) sA[tid + i * 256] = aReg[i];  // stride-1
    __syncthreads();

    // Stage E: intra-chunk part + norm
    #pragma unroll
    for (int i = 0; i < 16; ++i) {
        const int e = tid + i * 256;
        const int n = e >> 6, v = e & 63;
        const float* pa = sA + n * CHK;        // broadcast (n wave-uniform)
        const float* pv = sV + v * (CHK + 1);  // 2-way banked
        float acc = 0.f;
        for (int j = 0; j <= n; ++j) acc = fmaf(pa[j], pv[j], acc);  // uniform bound per wave
        accO[i] += acc;
    }
    if (tid < CHK) {
        const float* pa = sA + tid * CHK;
        float acc = normReg;
        for (int j = 0; j <= tid; ++j) acc += pa[j];
        sNorm[tid] = acc;
    }
    __syncthreads();

    // Stage F: divide and stage for transposed store
    #pragma unroll
    for (int i = 0; i < 16; ++i) {
        const int e = tid + i * 256;
        const int n = e >> 6, v = e & 63;
        sOut[n * (DV + 1) + v] = accO[i] / sNorm[n];
    }
    __syncthreads();

    // Stage G: coalesced global write (lanes along n)
    for (int e = tid; e < DV * CHK; e += 256) {
        const int v = e >> 6, n = e & 63;
        out[(bh * DV + v) * NSEQ + n0 + n] = sOut[n * (DV + 1) + v];
    }
}

extern "C" void kernel_launch(void* const* d_in, const int* in_sizes, int n_in,
                              void* d_out, int out_size, void* d_ws, size_t ws_size,
                              hipStream_t stream)
{
    const float* keys     = (const float*)d_in[0];
    const float* values   = (const float*)d_in[1];
    const float* queries  = (const float*)d_in[2];
    const float* features = (const float*)d_in[3];
    float* outp = (float*)d_out;

    // Workspace: S [BH][NC][M][DV] (8 MB) then z [BH][NC][M] (128 KB)
    float* wsS = (float*)d_ws;
    float* wsZ = wsS + (size_t)BH * NC * M * DV;

    favor_phase1<<<dim3(BH * NC), dim3(256), 0, stream>>>(keys, values, features, wsS, wsZ);
    const int per = M * DV + M;
    favor_phase2<<<dim3((BH * per + 255) / 256), dim3(256), 0, stream>>>(wsS, wsZ);
    favor_phase3<<<dim3(BH * NC), dim3(256), 0, stream>>>(keys, values, queries, features,
                                                          wsS, wsZ, outp);
}

// Round 2
// 91.664 us; speedup vs baseline: 2.1160x; 2.1160x over previous
//
#include <hip/hip_runtime.h>

// FAVOR+ causal linear attention via chunk-parallel bf16 MFMA.
// BH=8, D=DV=64, N=2048, M=128, chunk C=64, NC=32.
// Phase1: per-chunk S^T[v][m] = sum_n V[v][n] phiK[m][n] (bf16 out), z[m] (fp32)
// Phase2: exclusive prefix scan over chunks (S^T bf16, z fp32), in place
// Phase3: out = phiQ.S_prefix + causal(phiQ.phiK^T).V, / norm   -- all MFMA

#define BH 8
#define D 64
#define DV 64
#define NSEQ 2048
#define M 128
#define CHK 64
#define NC (NSEQ / CHK)
#define PHI_SCALE 0.08838834764831845f  // 1/sqrt(128)

typedef unsigned int uint;
typedef unsigned short ushort;
typedef __attribute__((ext_vector_type(8))) short bf16x8;
typedef __attribute__((ext_vector_type(4))) float f32x4;
#define MFMA16(a, b, c) __builtin_amdgcn_mfma_f32_16x16x32_bf16((a), (b), (c), 0, 0, 0)

__device__ __forceinline__ short f2bf(float x) {  // RNE truncate fp32->bf16
    uint u = __float_as_uint(x);
    u += 0x7fffu + ((u >> 16) & 1u);
    return (short)(u >> 16);
}
__device__ __forceinline__ float bf2f(short b) {
    return __uint_as_float(((uint)(ushort)b) << 16);
}

// ---------------- Phase 1 ----------------
__global__ __launch_bounds__(256) void favor_p1(
    const float* __restrict__ keys, const float* __restrict__ values,
    const float* __restrict__ features, ushort* __restrict__ St,
    float* __restrict__ z)
{
    const int bh = blockIdx.x >> 5, c = blockIdx.x & 31, n0 = c * CHK;
    const int tid = threadIdx.x;
    const int lane = tid & 63, wid = tid >> 6, quad = lane >> 4, l16 = lane & 15;

    __shared__ ulong2 smv[2048];               // 32 KB
    short* sF  = (short*)smv;                  // [128][64] bf16 F
    short* sPK = (short*)smv + 8192;           // [128][64] bf16 phiK [m][n]

    for (int i = tid; i < 8192; i += 256) sF[i] = f2bf(features[i]);
    __syncthreads();

    // phiK D[m][n] = F[m][d] . K[d][n]; wave wid -> n-tile wid
    {
        const float* Kb = keys + bh * D * NSEQ + n0 + 16 * wid + l16;
        bf16x8 bK[2];
        for (int h = 0; h < 2; ++h)
            for (int j = 0; j < 8; ++j)
                bK[h][j] = f2bf(Kb[(32 * h + 8 * quad + j) * NSEQ]);
        for (int mt = 0; mt < 8; ++mt) {
            f32x4 acc = {0.f, 0.f, 0.f, 0.f};
            for (int h = 0; h < 2; ++h) {
                bf16x8 aF = *(const bf16x8*)(sF + (16 * mt + l16) * 64 + 32 * h + 8 * quad);
                acc = MFMA16(aF, bK[h], acc);
            }
            for (int r = 0; r < 4; ++r)
                sPK[(16 * mt + 4 * quad + r) * 64 + 16 * wid + l16] =
                    f2bf(fmaxf(acc[r], 0.f) * PHI_SCALE);
        }
    }
    __syncthreads();

    // z[m] = sum_n phiK[m][n] (rotate column to spread LDS banks)
    if (tid < 128) {
        float s = 0.f;
        for (int n = 0; n < 64; ++n) s += bf2f(sPK[tid * 64 + ((n + tid) & 63)]);
        z[(bh * NC + c) * M + tid] = s;
    }

    // S^T D[v][m] = V[v][n] . phiK_B[n][m]; wave wid -> v-tile wid
    {
        const float* Vb = values + bh * DV * NSEQ + n0;
        bf16x8 aV[2];
        for (int h = 0; h < 2; ++h) {
            const float4* vp = (const float4*)(Vb + (16 * wid + l16) * NSEQ + 32 * h + 8 * quad);
            float4 v0 = vp[0], v1 = vp[1];
            aV[h][0] = f2bf(v0.x); aV[h][1] = f2bf(v0.y);
            aV[h][2] = f2bf(v0.z); aV[h][3] = f2bf(v0.w);
            aV[h][4] = f2bf(v1.x); aV[h][5] = f2bf(v1.y);
            aV[h][6] = f2bf(v1.z); aV[h][7] = f2bf(v1.w);
        }
        ushort* So = St + (size_t)(bh * NC + c) * (DV * M);
        for (int mt = 0; mt < 8; ++mt) {
            f32x4 acc = {0.f, 0.f, 0.f, 0.f};
            for (int h = 0; h < 2; ++h) {
                bf16x8 bP = *(const bf16x8*)(sPK + (16 * mt + l16) * 64 + 32 * h + 8 * quad);
                acc = MFMA16(aV[h], bP, acc);
            }
            for (int r = 0; r < 4; ++r)
                So[(16 * wid + 4 * quad + r) * M + 16 * mt + l16] = (ushort)f2bf(acc[r]);
        }
    }
}

// ---------------- Phase 2: exclusive prefix scans over chunks ----------------
__global__ __launch_bounds__(256) void favor_p2(ushort* __restrict__ St,
                                                float* __restrict__ z)
{
    const int gid = blockIdx.x * 256 + threadIdx.x;
    if (blockIdx.x < 256) {                       // S^T columns: 8*64*128 = 65536
        const int bh = gid >> 13, vm = gid & 8191;
        ushort* p = St + (size_t)bh * NC * 8192 + vm;
        float vals[NC];
        #pragma unroll
        for (int cc = 0; cc < NC; ++cc) vals[cc] = bf2f(p[cc * 8192]);
        float run = 0.f;
        #pragma unroll
        for (int cc = 0; cc < NC; ++cc) { p[cc * 8192] = (ushort)f2bf(run); run += vals[cc]; }
    } else {                                      // z columns: 8*128 = 1024
        const int i = gid - 65536;
        if (i < BH * M) {
            const int bh = i >> 7, m = i & 127;
            float* p = z + bh * NC * M + m;
            float vals[NC];
            #pragma unroll
            for (int cc = 0; cc < NC; ++cc) vals[cc] = p[cc * M];
            float run = 0.f;
            #pragma unroll
            for (int cc = 0; cc < NC; ++cc) { p[cc * M] = run; run += vals[cc]; }
        }
    }
}

// ---------------- Phase 3 ----------------
__global__ __launch_bounds__(256) void favor_p3(
    const float* __restrict__ keys, const float* __restrict__ values,
    const float* __restrict__ queries, const ushort* __restrict__ St,
    const float* __restrict__ z, const float* __restrict__ features,
    float* __restrict__ out)
{
    const int bh = blockIdx.x >> 5, c = blockIdx.x & 31, n0 = c * CHK;
    const int tid = threadIdx.x;
    const int lane = tid & 63, wid = tid >> 6, quad = lane >> 4, l16 = lane & 15;

    __shared__ ulong2 smv[3120];                  // 49920 B
    char* sm = (char*)smv;
    short* sF   = (short*)sm;                     // [0,16384)  F bf16 [128][64]
    short* sAm  = (short*)sm;                     // reuse: Amat bf16 [64][64]  [0,8192)
    short* sV   = (short*)(sm + 8192);            // reuse: V bf16 [64][64]     [8192,16384)
    short* sPQ  = (short*)(sm + 16384);           // phiQ^T bf16 [64][128]      [16384,32768)
    float* sOut = (float*)(sm + 16384);           // reuse: out [64][65] f32    [16384,33024)
    short* sPK  = (short*)(sm + 32768);           // phiK^T bf16 [64][128]      [32768,49152)
    float* sZ   = (float*)(sm + 49152);           // z_excl f32 [128]
    float* sNm  = (float*)(sm + 49664);           // norm f32 [64]

    for (int i = tid; i < 8192; i += 256) sF[i] = f2bf(features[i]);
    if (tid < 128) sZ[tid] = z[(bh * NC + c) * M + tid];
    __syncthreads();

    // phiQ^T[n][m], phiK^T[j][m]: D[n][m] = Q^T[n][d] . F_B[d][m]; wave -> row-tile wid
    {
        const float* Qb = queries + bh * D * NSEQ + n0 + 16 * wid + l16;
        const float* Kb = keys    + bh * D * NSEQ + n0 + 16 * wid + l16;
        bf16x8 aQ[2], aK[2];
        for (int h = 0; h < 2; ++h)
            for (int j = 0; j < 8; ++j) {
                const int d = 32 * h + 8 * quad + j;
                aQ[h][j] = f2bf(Qb[d * NSEQ]);
                aK[h][j] = f2bf(Kb[d * NSEQ]);
            }
        for (int mt = 0; mt < 8; ++mt) {
            f32x4 accQ = {0.f, 0.f, 0.f, 0.f}, accK = {0.f, 0.f, 0.f, 0.f};
            for (int h = 0; h < 2; ++h) {
                bf16x8 bF = *(const bf16x8*)(sF + (16 * mt + l16) * 64 + 32 * h + 8 * quad);
                accQ = MFMA16(aQ[h], bF, accQ);
                accK = MFMA16(aK[h], bF, accK);
            }
            for (int r = 0; r < 4; ++r) {
                const int row = (16 * wid + 4 * quad + r) * M + 16 * mt + l16;
                sPQ[row] = f2bf(fmaxf(accQ[r], 0.f) * PHI_SCALE);
                sPK[row] = f2bf(fmaxf(accK[r], 0.f) * PHI_SCALE);
            }
        }
    }
    __syncthreads();  // B1: phi tiles visible; sF reads complete

    // A2: D[n][v] += phiQ^T . S_excl (B-frags straight from global bf16)
    // C : Amat[n][j] = phiQ^T . phiK  (masked, rowsummed)
    f32x4 accO[4], accC[4];
    for (int t = 0; t < 4; ++t) { accO[t] = (f32x4){0.f,0.f,0.f,0.f}; accC[t] = (f32x4){0.f,0.f,0.f,0.f}; }
    {
        const ushort* Sb = St + (size_t)(bh * NC + c) * (DV * M);
        for (int mt = 0; mt < 4; ++mt) {
            bf16x8 aP = *(const bf16x8*)(sPQ + (16 * wid + l16) * M + 32 * mt + 8 * quad);
            for (int vt = 0; vt < 4; ++vt) {
                bf16x8 bS = *(const bf16x8*)(Sb + (16 * vt + l16) * M + 32 * mt + 8 * quad);
                accO[vt] = MFMA16(aP, bS, accO[vt]);
            }
            for (int jt = 0; jt < 4; ++jt) {
                bf16x8 bK2 = *(const bf16x8*)(sPK + (16 * jt + l16) * M + 32 * mt + 8 * quad);
                accC[jt] = MFMA16(aP, bK2, accC[jt]);
            }
        }
    }
    // causal mask + Amat store (aliases dead sF) + row sums for norm
    float rsum[4] = {0.f, 0.f, 0.f, 0.f};
    for (int jt = 0; jt < 4; ++jt)
        for (int r = 0; r < 4; ++r) {
            const int n = 16 * wid + 4 * quad + r;
            const int j = 16 * jt + l16;
            const float av = (j <= n) ? accC[jt][r] : 0.f;
            rsum[r] += av;
            sAm[n * 64 + j] = f2bf(av);
        }
    for (int r = 0; r < 4; ++r) {
        float s = rsum[r];
        s += __shfl_xor(s, 1); s += __shfl_xor(s, 2);
        s += __shfl_xor(s, 4); s += __shfl_xor(s, 8);
        if (l16 == 0) sNm[16 * wid + 4 * quad + r] = s;   // intra part of norm
    }
    __syncthreads();  // B2

    // stage V (bf16) + inter part of norm: phiQ[n] . z_excl
    for (int i = tid; i < 4096; i += 256) {
        const int v = i >> 6, j = i & 63;
        sV[v * 64 + j] = f2bf(values[(bh * DV + v) * NSEQ + n0 + j]);
    }
    if (tid < 64) {
        float s = 0.f;
        for (int mm = 0; mm < 128; ++mm) {
            const int m = (mm + 2 * tid) & 127;           // rotate: spread banks
            s += bf2f(sPQ[tid * M + m]) * sZ[m];
        }
        sNm[tid] += s;
    }
    __syncthreads();  // B3

    // E: D[n][v] += Amat[n][j] . V_B[j][v]  (accumulates onto A2's acc)
    for (int jh = 0; jh < 2; ++jh) {
        bf16x8 aA = *(const bf16x8*)(sAm + (16 * wid + l16) * 64 + 32 * jh + 8 * quad);
        for (int vt = 0; vt < 4; ++vt) {
            bf16x8 bV = *(const bf16x8*)(sV + (16 * vt + l16) * 64 + 32 * jh + 8 * quad);
            accO[vt] = MFMA16(aA, bV, accO[vt]);
        }
    }
    // epilogue: divide by norm, transpose-stage (pad 65 -> 2-way banks)
    for (int vt = 0; vt < 4; ++vt)
        for (int r = 0; r < 4; ++r) {
            const int n = 16 * wid + 4 * quad + r, v = 16 * vt + l16;
            sOut[n * 65 + v] = accO[vt][r] / sNm[n];
        }
    __syncthreads();  // B4

    for (int i = tid; i < 4096; i += 256) {
        const int v = i >> 6, n = i & 63;
        out[(bh * DV + v) * NSEQ + n0 + n] = sOut[n * 65 + v];
    }
}

extern "C" void kernel_launch(void* const* d_in, const int* in_sizes, int n_in,
                              void* d_out, int out_size, void* d_ws, size_t ws_size,
                              hipStream_t stream)
{
    (void)in_sizes; (void)n_in; (void)out_size; (void)ws_size;
    const float* keys     = (const float*)d_in[0];
    const float* values   = (const float*)d_in[1];
    const float* queries  = (const float*)d_in[2];
    const float* features = (const float*)d_in[3];
    float* outp = (float*)d_out;

    // ws: S^T bf16 [BH][NC][DV][M] (4 MB) then z fp32 [BH][NC][M] (128 KB)
    ushort* St = (ushort*)d_ws;
    float*  z  = (float*)((char*)d_ws + (size_t)BH * NC * DV * M * sizeof(ushort));

    favor_p1<<<dim3(BH * NC), dim3(256), 0, stream>>>(keys, values, features, St, z);
    favor_p2<<<dim3(260), dim3(256), 0, stream>>>(St, z);
    favor_p3<<<dim3(BH * NC), dim3(256), 0, stream>>>(keys, values, queries, St, z,
                                                      features, outp);
}